// Round 8
// baseline (942.325 us; speedup 1.0000x reference)
//
#include <hip/hip_runtime.h>
#include <hip/hip_bf16.h>
#include <stdint.h>

#define H 256
#define G 4096
#define TK 32     // k1 tile rows
#define T0 64     // k0 tile rows

typedef __attribute__((ext_vector_type(8))) short bf16x8;
typedef __attribute__((ext_vector_type(4))) float f32x4;

__device__ inline short f2bf(float f){
  union { float f; uint32_t u; } v; v.f = f;
  uint32_t r = (v.u + 0x7FFFu + ((v.u >> 16) & 1u)) >> 16;
  return (short)(uint16_t)r;
}
__device__ inline float bf2f(short s){
  union { float f; uint32_t u; } v; v.u = ((uint32_t)(uint16_t)s) << 16;
  return v.f;
}
__device__ inline float sigmoidf_(float x){ return 1.f / (1.f + __expf(-x)); }

// LDS-only barrier: does NOT drain vmcnt, so prefetched global loads stay in flight.
__device__ inline void ldsbar(){
  asm volatile("s_waitcnt lgkmcnt(0)" ::: "memory");
  __builtin_amdgcn_s_barrier();
}

// ---------------- weight conversion f32 -> bf16 ----------------
__global__ void conv_w(const float* __restrict__ w1, const float* __restrict__ wih,
                       const float* __restrict__ whh,
                       short* __restrict__ o1, short* __restrict__ oih, short* __restrict__ ohh){
  int i = blockIdx.x * 256 + threadIdx.x;
  if (i < H*H) o1[i] = f2bf(w1[i]);
  if (i < 3*H*H){ oih[i] = f2bf(wih[i]); ohh[i] = f2bf(whh[i]); }
}

// ---------------- K0: mean-pool sums + counts + write x_bf16 ----------------
__global__ __launch_bounds__(512, 6) void k0_pool(const float* __restrict__ x, const int* __restrict__ batch,
                                                  float* __restrict__ pool, float* __restrict__ counts,
                                                  short* __restrict__ xbf, int nNodes){
  __shared__ int   ng[T0];
  __shared__ float Pacc[8][H];
  __shared__ float Cacc[8];
  __shared__ int   spanSh;

  const int t = threadIdx.x;
  const int base = blockIdx.x * T0;
  const int c4 = (t & 63) * 4;
  const int r0 = (t >> 6) * 8;   // 8 row-groups of 8 rows

  // issue the big loads FIRST so they overlap all setup
  float4 v[8];
  #pragma unroll
  for (int i = 0; i < 8; ++i){
    int node = base + r0 + i;
    if (node < nNodes) v[i] = *(const float4*)(x + (size_t)node*H + c4);
    else v[i] = make_float4(0.f,0.f,0.f,0.f);
  }

  if (t < T0) ng[t] = (base + t < nNodes) ? batch[base + t] : -1;
  for (int u = t; u < 8*H; u += 512) ((float*)Pacc)[u] = 0.f;
  if (t < 8) Cacc[t] = 0.f;
  __syncthreads();

  if (t == 64){
    int lg = ng[0];
    for (int i = 1; i < T0; ++i){ int g = ng[i]; if (g >= 0) lg = g; }
    spanSh = (ng[0] >= 0) ? (lg - ng[0]) : -1;
  }

  // write bf16 copy of x
  if (xbf){
    #pragma unroll
    for (int i = 0; i < 8; ++i){
      int node = base + r0 + i;
      if (node < nNodes){
        ushort4 o;
        o.x = (uint16_t)f2bf(v[i].x); o.y = (uint16_t)f2bf(v[i].y);
        o.z = (uint16_t)f2bf(v[i].z); o.w = (uint16_t)f2bf(v[i].w);
        *(ushort4*)(xbf + (size_t)node*H + c4) = o;
      }
    }
  }
  __syncthreads();

  const int g0 = ng[0];
  const bool useLds = (spanSh >= 0) && (spanSh < 8);

  float ax=0.f, ay=0.f, az=0.f, aw=0.f;
  int cur = ng[r0];
  if (cur >= 0){
    #pragma unroll
    for (int i = 0; i < 8; ++i){
      int g = ng[r0 + i];
      if (g < 0) break;
      if (g != cur){
        if (useLds){
          atomicAdd(&Pacc[cur-g0][c4], ax);   atomicAdd(&Pacc[cur-g0][c4+1], ay);
          atomicAdd(&Pacc[cur-g0][c4+2], az); atomicAdd(&Pacc[cur-g0][c4+3], aw);
        } else {
          atomicAdd(&pool[(size_t)cur*H + c4], ax);   atomicAdd(&pool[(size_t)cur*H + c4+1], ay);
          atomicAdd(&pool[(size_t)cur*H + c4+2], az); atomicAdd(&pool[(size_t)cur*H + c4+3], aw);
        }
        ax=ay=az=aw=0.f; cur = g;
      }
      ax += v[i].x; ay += v[i].y; az += v[i].z; aw += v[i].w;
    }
    if (useLds){
      atomicAdd(&Pacc[cur-g0][c4], ax);   atomicAdd(&Pacc[cur-g0][c4+1], ay);
      atomicAdd(&Pacc[cur-g0][c4+2], az); atomicAdd(&Pacc[cur-g0][c4+3], aw);
    } else {
      atomicAdd(&pool[(size_t)cur*H + c4], ax);   atomicAdd(&pool[(size_t)cur*H + c4+1], ay);
      atomicAdd(&pool[(size_t)cur*H + c4+2], az); atomicAdd(&pool[(size_t)cur*H + c4+3], aw);
    }
  }
  if (t < T0 && ng[t] >= 0){
    if (useLds) atomicAdd(&Cacc[ng[t]-g0], 1.f);
    else        atomicAdd(&counts[ng[t]], 1.f);
  }
  __syncthreads();

  if (useLds){
    int nr = spanSh + 1;
    for (int u = t; u < nr*H; u += 512){
      int r = u >> 8, c = u & 255;
      float vv = Pacc[r][c];
      if (vv != 0.f) atomicAdd(&pool[(size_t)(g0+r)*H + c], vv);
    }
    if (t < nr && Cacc[t] != 0.f) atomicAdd(&counts[g0 + t], Cacc[t]);
  }
}

// ---------------- K0b: repr = pool / max(counts,1) ; also bf16 copy ----------------
__global__ void k0b_div(const float* __restrict__ pool, const float* __restrict__ counts,
                        float* __restrict__ repr, short* __restrict__ rbf){
  size_t i = (size_t)blockIdx.x * 256 + threadIdx.x;
  int g = (int)(i >> 8);
  float v = pool[i] / fmaxf(counts[g], 1.f);
  repr[i] = v;
  rbf[i] = f2bf(v);
}

// ---------------- K1: persistent fused gate MLP + weighted pooling ----------------
// x' = bf16(bf16(x) + bf16(r[g]));  h = relu(W1*x' + b1); gate = sigmoid(w2.h + b2)
// pool'[g] += gate * x' ; gsum[g] += gate   (k2 corrects: new = (pool' - gsum*r)/cnt)
template<bool BF>
__global__ __launch_bounds__(512) __attribute__((amdgpu_waves_per_eu(3, 4)))
void k1_gate(
    const float* __restrict__ xf32, const short* __restrict__ xbf,
    const short* __restrict__ rbf, const float* __restrict__ reprf,
    const int* __restrict__ batch,
    const short* __restrict__ w1bf, const float* __restrict__ w2v_,
    const float* __restrict__ b1v_, const float* __restrict__ b2p,
    float* __restrict__ pool, float* __restrict__ gsum,
    int nNodes, int nTiles, int nBlk){

  __shared__ short Ain[2][TK][H + 8];     // 33.8 KB double-buffered x' tiles
  __shared__ float Pacc[16][H];           // 16 KB sliding-window accumulator
  __shared__ float partials[8][TK];       // 1 KB
  __shared__ float gates[TK];
  __shared__ float Gacc[16];
  __shared__ int   ngS[2][TK];
  __shared__ char  ldspad[3328];          // pin 2 blocks/CU

  const int t    = threadIdx.x;
  const int wid  = t >> 6;      // 0..7 : col-block of 32
  const int lane = t & 63;
  const int l15  = lane & 15;
  const int l4   = lane >> 4;
  const int r0r  = t >> 5;      // my row (0..15); second row = +16
  const int cg8  = (t & 31) * 8;

  if (t == 0) *(volatile char*)&ldspad[0] = 1;

  const int b = blockIdx.x;
  const int tile0 = (int)(((long long)b * nTiles) / nBlk);
  const int tile1 = (int)(((long long)(b+1) * nTiles) / nBlk);
  if (tile0 >= tile1) return;

  for (int u = t; u < 16*H; u += 512) ((float*)Pacc)[u] = 0.f;
  if (t < 16) Gacc[t] = 0.f;

  // W1 slices for this wave's 32 output cols, in registers (loaded once per block)
  bf16x8 Bf0[8], Bf1[8];
  {
    const short* wp0 = w1bf + (size_t)(wid*32 + l15)*H + l4*8;
    #pragma unroll
    for (int kc = 0; kc < 8; ++kc){
      Bf0[kc] = *(const bf16x8*)(wp0 + kc*32);
      Bf1[kc] = *(const bf16x8*)(wp0 + 16*H + kc*32);
    }
  }
  const float w2v0 = w2v_[wid*32 + l15];
  const float w2v1 = w2v_[wid*32 + 16 + l15];
  const float b1v0 = b1v_[wid*32 + l15];
  const float b1v1 = b1v_[wid*32 + 16 + l15];
  const float b2v  = b2p[0];

  int gw0 = batch[tile0 * TK];   // window base (block-uniform)

  // ---- prefetch state ----
  bf16x8 xv[2], rv[2];
  float4 xf[2][2], rf[2][2];
  int ngv = -1;

  auto bload = [&](int tile, int ro)->int{
    int node = tile*TK + r0r + ro;
    return (node < nNodes) ? batch[node] : 0;
  };
  auto issue = [&](int tile, int bg0, int bg1){
    int base = tile * TK;
    int n0 = base + r0r, n1 = n0 + 16;
    if constexpr (BF){
      xv[0] = (n0 < nNodes) ? *(const bf16x8*)(xbf + (size_t)n0*H + cg8) : (bf16x8)0;
      xv[1] = (n1 < nNodes) ? *(const bf16x8*)(xbf + (size_t)n1*H + cg8) : (bf16x8)0;
      rv[0] = (n0 < nNodes) ? *(const bf16x8*)(rbf + (size_t)bg0*H + cg8) : (bf16x8)0;
      rv[1] = (n1 < nNodes) ? *(const bf16x8*)(rbf + (size_t)bg1*H + cg8) : (bf16x8)0;
    } else {
      if (n0 < nNodes){
        const float4* xp = (const float4*)(xf32 + (size_t)n0*H + cg8);
        const float4* rp = (const float4*)(reprf + (size_t)bg0*H + cg8);
        xf[0][0] = xp[0]; xf[0][1] = xp[1]; rf[0][0] = rp[0]; rf[0][1] = rp[1];
      } else { xf[0][0]=xf[0][1]=rf[0][0]=rf[0][1]=make_float4(0.f,0.f,0.f,0.f); }
      if (n1 < nNodes){
        const float4* xp = (const float4*)(xf32 + (size_t)n1*H + cg8);
        const float4* rp = (const float4*)(reprf + (size_t)bg1*H + cg8);
        xf[1][0] = xp[0]; xf[1][1] = xp[1]; rf[1][0] = rp[0]; rf[1][1] = rp[1];
      } else { xf[1][0]=xf[1][1]=rf[1][0]=rf[1][1]=make_float4(0.f,0.f,0.f,0.f); }
    }
    int n2 = base + (t & 31);
    ngv = (n2 < nNodes) ? batch[n2] : -1;
  };

  // prologue: batch 1 tile ahead of x/r, x/r 1 tile ahead of compute
  int bgA0 = bload(tile0, 0), bgA1 = bload(tile0, 16);
  issue(tile0, bgA0, bgA1);
  int bgB0 = bload(tile0+1, 0), bgB1 = bload(tile0+1, 16);

  int buf = 0;
  for (int tile = tile0; tile < tile1; ++tile, buf ^= 1){
    // 1. stage x' = bf16(x)+bf16(r) to LDS
    #pragma unroll
    for (int q = 0; q < 2; ++q){
      bf16x8 o;
      if constexpr (BF){
        #pragma unroll
        for (int k = 0; k < 8; ++k) o[k] = f2bf(bf2f(xv[q][k]) + bf2f(rv[q][k]));
      } else {
        float4 a0 = xf[q][0], a1 = xf[q][1], c0 = rf[q][0], c1 = rf[q][1];
        o[0]=f2bf(a0.x+c0.x); o[1]=f2bf(a0.y+c0.y); o[2]=f2bf(a0.z+c0.z); o[3]=f2bf(a0.w+c0.w);
        o[4]=f2bf(a1.x+c1.x); o[5]=f2bf(a1.y+c1.y); o[6]=f2bf(a1.z+c1.z); o[7]=f2bf(a1.w+c1.w);
      }
      *(bf16x8*)(&Ain[buf][r0r + q*16][cg8]) = o;
    }
    if (t < TK) ngS[buf][t] = ngv;

    // 2. issue prefetch for t+1 (batch already resident), batch for t+2
    if (tile + 1 < tile1){
      issue(tile + 1, bgB0, bgB1);
      bgB0 = bload(tile + 2, 0); bgB1 = bload(tile + 2, 16);
    }

    ldsbar();   // B2: Ain[buf]+ngS[buf] visible; prev pooling complete

    // 3. sliding-window flush (block-uniform; zeroing ordered by B3)
    int gfirst = ngS[buf][0];
    int glast;
    if (tile*TK + TK <= nNodes) glast = ngS[buf][TK-1];
    else {
      glast = gfirst;
      for (int i = TK-1; i > 0; --i){ int g = ngS[buf][i]; if (g >= 0){ glast = g; break; } }
    }
    if (gfirst >= 0 && glast >= gw0 + 16){
      for (int u = t; u < 16*H; u += 512){
        float vv = ((float*)Pacc)[u];
        if (vv != 0.f){
          int r = u >> 8, c = u & 255;
          atomicAdd(&pool[(size_t)(gw0 + r)*H + c], vv);
          ((float*)Pacc)[u] = 0.f;
        }
      }
      if (t < 16){
        float gv2 = Gacc[t];
        if (gv2 != 0.f) atomicAdd(&gsum[gw0 + t], gv2);
        Gacc[t] = 0.f;
      }
      gw0 = gfirst;
    }

    // 4. MFMA: rows 0..31, cols wid*32..+32
    f32x4 acc0[2], acc1[2];
    #pragma unroll
    for (int r = 0; r < 2; ++r){ acc0[r] = (f32x4){0.f,0.f,0.f,0.f}; acc1[r] = (f32x4){0.f,0.f,0.f,0.f}; }
    #pragma unroll
    for (int kc = 0; kc < 8; ++kc){
      #pragma unroll
      for (int r = 0; r < 2; ++r){
        bf16x8 a = *(bf16x8*)(&Ain[buf][r*16 + l15][kc*32 + l4*8]);
        acc0[r] = __builtin_amdgcn_mfma_f32_16x16x32_bf16(a, Bf0[kc], acc0[r], 0, 0, 0);
        acc1[r] = __builtin_amdgcn_mfma_f32_16x16x32_bf16(a, Bf1[kc], acc1[r], 0, 0, 0);
      }
    }

    // 5. epilogue: pure-register w2·relu(acc+b1), then shuffle reduce
    float p[2][4];
    #pragma unroll
    for (int r = 0; r < 2; ++r)
      #pragma unroll
      for (int j = 0; j < 4; ++j){
        float h0 = fmaxf(acc0[r][j] + b1v0, 0.f);
        float h1 = fmaxf(acc1[r][j] + b1v1, 0.f);
        p[r][j] = w2v0*h0 + w2v1*h1;
      }
    #pragma unroll
    for (int off = 1; off < 16; off <<= 1){
      #pragma unroll
      for (int r = 0; r < 2; ++r)
        #pragma unroll
        for (int j = 0; j < 4; ++j) p[r][j] += __shfl_xor(p[r][j], off);
    }
    if (l15 == 0){
      #pragma unroll
      for (int r = 0; r < 2; ++r)
        #pragma unroll
        for (int j = 0; j < 4; ++j) partials[wid][r*16 + l4*4 + j] = p[r][j];
    }
    ldsbar();   // B3: partials visible (also orders Pacc/Gacc zeroing)

    if (t < TK){
      float s = b2v;
      #pragma unroll
      for (int w = 0; w < 8; ++w) s += partials[w][t];
      gates[t] = sigmoidf_(s);
    }
    ldsbar();   // B4: gates visible

    // 6. weighted pooling + gatesum into sliding window
    {
      const int c2 = (t & 127) * 2;
      const int rr0 = (t >> 7) * 8;   // 4 row-groups of 8 rows

      float ax = 0.f, ay = 0.f;
      int cur = ngS[buf][rr0];
      if (cur >= 0){
        #pragma unroll
        for (int i = 0; i < 8; ++i){
          int g = ngS[buf][rr0 + i];
          if (g < 0) break;
          if (g != cur){
            int idx = cur - gw0;
            if (idx >= 0 && idx < 16){ atomicAdd(&Pacc[idx][c2], ax); atomicAdd(&Pacc[idx][c2+1], ay); }
            else { atomicAdd(&pool[(size_t)cur*H + c2], ax); atomicAdd(&pool[(size_t)cur*H + c2+1], ay); }
            ax = ay = 0.f; cur = g;
          }
          uint32_t av = *(const uint32_t*)(&Ain[buf][rr0 + i][c2]);
          float gv = gates[rr0 + i];
          ax += gv * bf2f((short)(uint16_t)(av & 0xFFFFu));
          ay += gv * bf2f((short)(uint16_t)(av >> 16));
        }
        int idx = cur - gw0;
        if (idx >= 0 && idx < 16){ atomicAdd(&Pacc[idx][c2], ax); atomicAdd(&Pacc[idx][c2+1], ay); }
        else { atomicAdd(&pool[(size_t)cur*H + c2], ax); atomicAdd(&pool[(size_t)cur*H + c2+1], ay); }
      }
      if ((t & 127) == 0 && ngS[buf][rr0] >= 0){
        float gs2 = 0.f; int cg = ngS[buf][rr0];
        #pragma unroll
        for (int i = 0; i < 8; ++i){
          int g = ngS[buf][rr0 + i];
          if (g < 0) break;
          if (g != cg){
            int idx = cg - gw0;
            if (idx >= 0 && idx < 16) atomicAdd(&Gacc[idx], gs2);
            else atomicAdd(&gsum[cg], gs2);
            gs2 = 0.f; cg = g;
          }
          gs2 += gates[rr0 + i];
        }
        int idx = cg - gw0;
        if (idx >= 0 && idx < 16) atomicAdd(&Gacc[idx], gs2);
        else atomicAdd(&gsum[cg], gs2);
      }
    }
  }

  // final window flush
  ldsbar();
  for (int u = t; u < 16*H; u += 512){
    float vv = ((float*)Pacc)[u];
    if (vv != 0.f){
      int r = u >> 8, c = u & 255;
      atomicAdd(&pool[(size_t)(gw0 + r)*H + c], vv);
    }
  }
  if (t < 16 && Gacc[t] != 0.f) atomicAdd(&gsum[gw0 + t], Gacc[t]);
}

// ---------------- K2: fused GRU over 16 graphs/block ----------------
__global__ __launch_bounds__(256) void k2_gru(const float* __restrict__ pool,
    const float* __restrict__ gsum, const float* __restrict__ counts,
    const float* __restrict__ repr_in,
    const short* __restrict__ wihbf, const short* __restrict__ whhbf,
    const float* __restrict__ bih, const float* __restrict__ bhh,
    float* __restrict__ repr_out, short* __restrict__ rbf_out){

  __shared__ short Anew[16][H + 8];
  __shared__ short Aold[16][H + 8];
  __shared__ float hold[16][H];
  __shared__ float srz[16][2*H];
  __shared__ float sni[16][H];
  __shared__ float snh[16][H];

  const int t    = threadIdx.x;
  const int wid  = t >> 6;
  const int lane = t & 63;
  const int l15  = lane & 15;
  const int l4   = lane >> 4;
  const int g0   = blockIdx.x * 16;

  for (int u = t; u < 16*H; u += 256){
    int row = u >> 8, c = u & 255;
    int g = g0 + row;
    float cnt = fmaxf(counts[g], 1.f);
    float rin = repr_in[(size_t)g*H + c];
    float rinb = bf2f(f2bf(rin));            // same rounded r as k1 used in x'
    float nr  = (pool[(size_t)g*H + c] - gsum[g]*rinb) / cnt;
    Anew[row][c] = f2bf(nr);
    Aold[row][c] = f2bf(rin);
    hold[row][c] = rin;
  }
  __syncthreads();

  f32x4 ai[12], ah[12];
  #pragma unroll
  for (int i = 0; i < 12; ++i){ ai[i] = (f32x4){0.f,0.f,0.f,0.f}; ah[i] = (f32x4){0.f,0.f,0.f,0.f}; }

  for (int kc = 0; kc < 8; ++kc){
    bf16x8 an = *(bf16x8*)(&Anew[l15][kc*32 + l4*8]);
    bf16x8 ao = *(bf16x8*)(&Aold[l15][kc*32 + l4*8]);
    #pragma unroll
    for (int nt = 0; nt < 12; ++nt){
      int n = wid*192 + nt*16 + l15;
      bf16x8 bi = *(const bf16x8*)(wihbf + (size_t)n*H + kc*32 + l4*8);
      bf16x8 bh = *(const bf16x8*)(whhbf + (size_t)n*H + kc*32 + l4*8);
      ai[nt] = __builtin_amdgcn_mfma_f32_16x16x32_bf16(an, bi, ai[nt], 0, 0, 0);
      ah[nt] = __builtin_amdgcn_mfma_f32_16x16x32_bf16(ao, bh, ah[nt], 0, 0, 0);
    }
  }

  #pragma unroll
  for (int nt = 0; nt < 12; ++nt){
    int n = wid*192 + nt*16 + l15;
    float bi = bih[n], bh = bhh[n];
    #pragma unroll
    for (int r = 0; r < 4; ++r){
      int row = l4*4 + r;
      float si = ai[nt][r] + bi;
      float sh = ah[nt][r] + bh;
      if (n < 2*H) srz[row][n] = si + sh;
      else { sni[row][n - 2*H] = si; snh[row][n - 2*H] = sh; }
    }
  }
  __syncthreads();

  for (int u = t; u < 16*H; u += 256){
    int row = u >> 8, c = u & 255;
    float rr = sigmoidf_(srz[row][c]);
    float zz = sigmoidf_(srz[row][H + c]);
    float nn = tanhf(sni[row][c] + rr * snh[row][c]);
    float hv = (1.f - zz) * nn + zz * hold[row][c];
    float out = fmaxf(hv, 0.f);
    repr_out[(size_t)(g0 + row)*H + c] = out;
    rbf_out[(size_t)(g0 + row)*H + c] = f2bf(out);
  }
}

extern "C" void kernel_launch(void* const* d_in, const int* in_sizes, int n_in,
                              void* d_out, int out_size, void* d_ws, size_t ws_size,
                              hipStream_t stream){
  const float* x    = (const float*)d_in[0];
  const float* w1   = (const float*)d_in[1];
  const float* b1   = (const float*)d_in[2];
  const float* w2   = (const float*)d_in[3];
  const float* b2   = (const float*)d_in[4];
  const float* wih  = (const float*)d_in[5];
  const float* whh  = (const float*)d_in[6];
  const float* bih  = (const float*)d_in[7];
  const float* bhh  = (const float*)d_in[8];
  const int*   batch= (const int*)d_in[9];
  const int N = in_sizes[9];

  char* ws = (char*)d_ws;
  short* w1bf   = (short*)(ws + 0);            // 128 KB
  short* wihbf  = (short*)(ws + (1u<<17));     // 384 KB @128K
  short* whhbf  = (short*)(ws + (1u<<19));     // 384 KB @512K
  float* counts = (float*)(ws + 917504);       // 16 KB @896K
  float* gsum   = (float*)(ws + 933888);       // 16 KB @912K
  float* pool   = (float*)(ws + (1u<<20));     // 4 MB @1M
  float* repr   = (float*)(ws + (1u<<20) + (1u<<22)); // 4 MB @5M
  short* rbf    = (short*)(ws + (10u<<20));    // 2 MB @10M
  float* outp   = (float*)d_out;

  const size_t XBF_OFF = (size_t)16u << 20;    // 16 MB
  const bool useXbf = ws_size >= XBF_OFF + (size_t)N * H * sizeof(short);
  short* xbf = useXbf ? (short*)(ws + XBF_OFF) : nullptr;

  const int nTiles  = (N + TK - 1) / TK;       // 15625
  const int nBlkK1  = 512;                     // 2 persistent blocks / CU
  const int nBlk0   = (N + T0 - 1) / T0;

  conv_w<<<768, 256, 0, stream>>>(w1, wih, whh, w1bf, wihbf, whhbf);

  hipMemsetAsync(counts, 0, G*sizeof(float), stream);
  hipMemsetAsync(pool, 0, (size_t)G*H*sizeof(float), stream);
  k0_pool<<<nBlk0, 512, 0, stream>>>(x, batch, pool, counts, xbf, N);
  k0b_div<<<G*H/256, 256, 0, stream>>>(pool, counts, repr, rbf);

  for (int ts = 0; ts < 2; ++ts){
    hipMemsetAsync(pool, 0, (size_t)G*H*sizeof(float), stream);
    hipMemsetAsync(gsum, 0, G*sizeof(float), stream);
    if (useXbf)
      k1_gate<true><<<nBlkK1, 512, 0, stream>>>(x, xbf, rbf, repr, batch, w1bf, w2, b1, b2,
                                                pool, gsum, N, nTiles, nBlkK1);
    else
      k1_gate<false><<<nBlkK1, 512, 0, stream>>>(x, xbf, rbf, repr, batch, w1bf, w2, b1, b2,
                                                 pool, gsum, N, nTiles, nBlkK1);
    k2_gru<<<G/16, 256, 0, stream>>>(pool, gsum, counts, repr, wihbf, whhbf, bih, bhh,
                                     (ts == 0) ? repr : outp, rbf);
  }
}

// Round 9
// 846.644 us; speedup vs baseline: 1.1130x; 1.1130x over previous
//
#include <hip/hip_runtime.h>
#include <hip/hip_bf16.h>
#include <stdint.h>

#define H 256
#define G 4096
#define TK 32     // k1 tile rows
#define T0 64     // k0 tile rows

typedef __attribute__((ext_vector_type(8))) short bf16x8;
typedef __attribute__((ext_vector_type(4))) float f32x4;

__device__ inline short f2bf(float f){
  union { float f; uint32_t u; } v; v.f = f;
  uint32_t r = (v.u + 0x7FFFu + ((v.u >> 16) & 1u)) >> 16;
  return (short)(uint16_t)r;
}
__device__ inline float bf2f(short s){
  union { float f; uint32_t u; } v; v.u = ((uint32_t)(uint16_t)s) << 16;
  return v.f;
}
__device__ inline float sigmoidf_(float x){ return 1.f / (1.f + __expf(-x)); }

// LDS-only barrier: does NOT drain vmcnt, so prefetched global loads stay in flight.
__device__ inline void ldsbar(){
  asm volatile("s_waitcnt lgkmcnt(0)" ::: "memory");
  __builtin_amdgcn_s_barrier();
}

// ---------------- weight conversion f32 -> bf16 ----------------
__global__ void conv_w(const float* __restrict__ w1, const float* __restrict__ wih,
                       const float* __restrict__ whh,
                       short* __restrict__ o1, short* __restrict__ oih, short* __restrict__ ohh){
  int i = blockIdx.x * 256 + threadIdx.x;
  if (i < H*H) o1[i] = f2bf(w1[i]);
  if (i < 3*H*H){ oih[i] = f2bf(wih[i]); ohh[i] = f2bf(whh[i]); }
}

// ---------------- K0: mean-pool sums + counts + write x_bf16 ----------------
__global__ __launch_bounds__(512, 6) void k0_pool(const float* __restrict__ x, const int* __restrict__ batch,
                                                  float* __restrict__ pool, float* __restrict__ counts,
                                                  short* __restrict__ xbf, int nNodes){
  __shared__ int   ng[T0];
  __shared__ float Pacc[8][H];
  __shared__ float Cacc[8];
  __shared__ int   spanSh;

  const int t = threadIdx.x;
  const int base = blockIdx.x * T0;
  const int c4 = (t & 63) * 4;
  const int r0 = (t >> 6) * 8;   // 8 row-groups of 8 rows

  // issue the big loads FIRST so they overlap all setup
  float4 v[8];
  #pragma unroll
  for (int i = 0; i < 8; ++i){
    int node = base + r0 + i;
    if (node < nNodes) v[i] = *(const float4*)(x + (size_t)node*H + c4);
    else v[i] = make_float4(0.f,0.f,0.f,0.f);
  }

  if (t < T0) ng[t] = (base + t < nNodes) ? batch[base + t] : -1;
  for (int u = t; u < 8*H; u += 512) ((float*)Pacc)[u] = 0.f;
  if (t < 8) Cacc[t] = 0.f;
  __syncthreads();

  if (t == 64){
    int lg = ng[0];
    for (int i = 1; i < T0; ++i){ int g = ng[i]; if (g >= 0) lg = g; }
    spanSh = (ng[0] >= 0) ? (lg - ng[0]) : -1;
  }

  // write bf16 copy of x
  if (xbf){
    #pragma unroll
    for (int i = 0; i < 8; ++i){
      int node = base + r0 + i;
      if (node < nNodes){
        ushort4 o;
        o.x = (uint16_t)f2bf(v[i].x); o.y = (uint16_t)f2bf(v[i].y);
        o.z = (uint16_t)f2bf(v[i].z); o.w = (uint16_t)f2bf(v[i].w);
        *(ushort4*)(xbf + (size_t)node*H + c4) = o;
      }
    }
  }
  __syncthreads();

  const int g0 = ng[0];
  const bool useLds = (spanSh >= 0) && (spanSh < 8);

  float ax=0.f, ay=0.f, az=0.f, aw=0.f;
  int cur = ng[r0];
  if (cur >= 0){
    #pragma unroll
    for (int i = 0; i < 8; ++i){
      int g = ng[r0 + i];
      if (g < 0) break;
      if (g != cur){
        if (useLds){
          atomicAdd(&Pacc[cur-g0][c4], ax);   atomicAdd(&Pacc[cur-g0][c4+1], ay);
          atomicAdd(&Pacc[cur-g0][c4+2], az); atomicAdd(&Pacc[cur-g0][c4+3], aw);
        } else {
          atomicAdd(&pool[(size_t)cur*H + c4], ax);   atomicAdd(&pool[(size_t)cur*H + c4+1], ay);
          atomicAdd(&pool[(size_t)cur*H + c4+2], az); atomicAdd(&pool[(size_t)cur*H + c4+3], aw);
        }
        ax=ay=az=aw=0.f; cur = g;
      }
      ax += v[i].x; ay += v[i].y; az += v[i].z; aw += v[i].w;
    }
    if (useLds){
      atomicAdd(&Pacc[cur-g0][c4], ax);   atomicAdd(&Pacc[cur-g0][c4+1], ay);
      atomicAdd(&Pacc[cur-g0][c4+2], az); atomicAdd(&Pacc[cur-g0][c4+3], aw);
    } else {
      atomicAdd(&pool[(size_t)cur*H + c4], ax);   atomicAdd(&pool[(size_t)cur*H + c4+1], ay);
      atomicAdd(&pool[(size_t)cur*H + c4+2], az); atomicAdd(&pool[(size_t)cur*H + c4+3], aw);
    }
  }
  if (t < T0 && ng[t] >= 0){
    if (useLds) atomicAdd(&Cacc[ng[t]-g0], 1.f);
    else        atomicAdd(&counts[ng[t]], 1.f);
  }
  __syncthreads();

  if (useLds){
    int nr = spanSh + 1;
    for (int u = t; u < nr*H; u += 512){
      int r = u >> 8, c = u & 255;
      float vv = Pacc[r][c];
      if (vv != 0.f) atomicAdd(&pool[(size_t)(g0+r)*H + c], vv);
    }
    if (t < nr && Cacc[t] != 0.f) atomicAdd(&counts[g0 + t], Cacc[t]);
  }
}

// ---------------- K0b: repr = pool / max(counts,1) ----------------
__global__ void k0b_div(const float* __restrict__ pool, const float* __restrict__ counts,
                        float* __restrict__ repr){
  size_t i = (size_t)blockIdx.x * 256 + threadIdx.x;
  int g = (int)(i >> 8);
  repr[i] = pool[i] / fmaxf(counts[g], 1.f);
}

// ---------------- KT: hg[g] = W1 * bf16(repr[g]) + b1 ----------------
__global__ __launch_bounds__(256) void kT_hg(const float* __restrict__ repr,
    const short* __restrict__ w1bf, const float* __restrict__ b1,
    float* __restrict__ hg){
  __shared__ short Ar[16][H + 8];
  const int t    = threadIdx.x;
  const int wid  = t >> 6;
  const int lane = t & 63;
  const int l15  = lane & 15;
  const int l4   = lane >> 4;
  const int g0   = blockIdx.x * 16;

  for (int u = t; u < 16*32; u += 256){
    int row = u >> 5, cg = u & 31;
    int c0 = cg * 8;
    const float4* rp = (const float4*)(repr + (size_t)(g0+row)*H + c0);
    float4 r0 = rp[0], r1 = rp[1];
    bf16x8 o;
    o[0]=f2bf(r0.x); o[1]=f2bf(r0.y); o[2]=f2bf(r0.z); o[3]=f2bf(r0.w);
    o[4]=f2bf(r1.x); o[5]=f2bf(r1.y); o[6]=f2bf(r1.z); o[7]=f2bf(r1.w);
    *(bf16x8*)(&Ar[row][c0]) = o;
  }
  __syncthreads();

  f32x4 acc[4];
  #pragma unroll
  for (int i = 0; i < 4; ++i) acc[i] = (f32x4){0.f,0.f,0.f,0.f};
  #pragma unroll
  for (int kc = 0; kc < 8; ++kc){
    bf16x8 a = *(bf16x8*)(&Ar[l15][kc*32 + l4*8]);
    #pragma unroll
    for (int nt = 0; nt < 4; ++nt){
      int col = wid*64 + nt*16 + l15;
      bf16x8 b = *(const bf16x8*)(w1bf + (size_t)col*H + kc*32 + l4*8);
      acc[nt] = __builtin_amdgcn_mfma_f32_16x16x32_bf16(a, b, acc[nt], 0, 0, 0);
    }
  }
  #pragma unroll
  for (int nt = 0; nt < 4; ++nt){
    int col = wid*64 + nt*16 + l15;
    float b1v = b1[col];
    #pragma unroll
    for (int j = 0; j < 4; ++j){
      int row = l4*4 + j;
      hg[(size_t)(g0+row)*H + col] = acc[nt][j] + b1v;
    }
  }
}

// ---------------- K1: persistent fused gate MLP + weighted pooling ----------------
// h = relu(W1*bf16(x) + hg[g]); gate = sigmoid(w2.h + b2); pool[g] += gate * bf16(x)
// Depth-2 register prefetch (xvA/xvB) so each tile's loads are issued ~2 tile-chains
// before consumption. Operating point pinned at 2 blocks/CU, 4 waves/EU (<=128 VGPR).
template<bool BF>
__global__ __launch_bounds__(512) __attribute__((amdgpu_waves_per_eu(3, 4)))
void k1_gate(
    const float* __restrict__ xf32, const short* __restrict__ xbf,
    const int* __restrict__ batch, const float* __restrict__ hg,
    const short* __restrict__ w1bf, const float* __restrict__ w2,
    const float* __restrict__ b2p, float* __restrict__ pool,
    int nNodes, int nTiles, int nBlk){

  __shared__ short Ain[2][TK][H + 8];     // 33.8 KB double-buffered
  __shared__ float Pacc[16][H];           // 16 KB sliding-window accumulator
  __shared__ float partials[8][TK];       // 1 KB
  __shared__ float gates[TK];
  __shared__ int   ngS[2][TK];
  __shared__ char  ldspad[3328];          // pin 2 blocks/CU -> allocator targets 4 waves/EU

  const int t    = threadIdx.x;
  const int wid  = t >> 6;      // 0..7 : col-block of 32
  const int lane = t & 63;
  const int l15  = lane & 15;
  const int l4   = lane >> 4;
  const int r0r  = t >> 5;      // my row (0..15); second row = +16
  const int cg8  = (t & 31) * 8;

  if (t == 0) *(volatile char*)&ldspad[0] = 1;

  const int b = blockIdx.x;
  const int tile0 = (int)(((long long)b * nTiles) / nBlk);
  const int tile1 = (int)(((long long)(b+1) * nTiles) / nBlk);
  if (tile0 >= tile1) return;

  for (int u = t; u < 16*H; u += 512) ((float*)Pacc)[u] = 0.f;

  // W1 slices for this wave's 32 output cols, in registers (loaded once per block)
  bf16x8 Bf0[8], Bf1[8];
  {
    const short* wp0 = w1bf + (size_t)(wid*32 + l15)*H + l4*8;
    #pragma unroll
    for (int kc = 0; kc < 8; ++kc){
      Bf0[kc] = *(const bf16x8*)(wp0 + kc*32);
      Bf1[kc] = *(const bf16x8*)(wp0 + 16*H + kc*32);
    }
  }
  const float w2v0 = w2[wid*32 + l15];
  const float w2v1 = w2[wid*32 + 16 + l15];
  const float b2v  = b2p[0];

  int gw0 = batch[tile0 * TK];   // window base (block-uniform)

  // ---- depth-2 prefetch state (static names, no runtime indexing) ----
  bf16x8 xvA[2], xvB[2];
  float4 xfA[2][2], xfB[2][2];
  int ngvA = -1, ngvB = -1;

  auto issueT = [&](int tile, bf16x8 (&xv)[2], float4 (&xf)[2][2], int &ngv){
    int base = tile * TK;
    int n0 = base + r0r, n1 = n0 + 16;
    if constexpr (BF){
      xv[0] = (n0 < nNodes) ? *(const bf16x8*)(xbf + (size_t)n0*H + cg8) : (bf16x8)0;
      xv[1] = (n1 < nNodes) ? *(const bf16x8*)(xbf + (size_t)n1*H + cg8) : (bf16x8)0;
    } else {
      if (n0 < nNodes){
        const float4* xp = (const float4*)(xf32 + (size_t)n0*H + cg8);
        xf[0][0] = xp[0]; xf[0][1] = xp[1];
      } else { xf[0][0] = make_float4(0.f,0.f,0.f,0.f); xf[0][1] = make_float4(0.f,0.f,0.f,0.f); }
      if (n1 < nNodes){
        const float4* xp = (const float4*)(xf32 + (size_t)n1*H + cg8);
        xf[1][0] = xp[0]; xf[1][1] = xp[1];
      } else { xf[1][0] = make_float4(0.f,0.f,0.f,0.f); xf[1][1] = make_float4(0.f,0.f,0.f,0.f); }
    }
    if (t < TK){
      int node = base + t;
      ngv = (node < nNodes) ? batch[node] : -1;
    }
  };

  auto body = [&](int tile, bf16x8 (&xv)[2], float4 (&xf)[2][2], int &ngv, int buf){
    // 1. write staged tile to LDS
    #pragma unroll
    for (int q = 0; q < 2; ++q){
      bf16x8 o;
      if constexpr (BF) o = xv[q];
      else {
        float4 a = xf[q][0], c = xf[q][1];
        o[0]=f2bf(a.x); o[1]=f2bf(a.y); o[2]=f2bf(a.z); o[3]=f2bf(a.w);
        o[4]=f2bf(c.x); o[5]=f2bf(c.y); o[6]=f2bf(c.z); o[7]=f2bf(c.w);
      }
      *(bf16x8*)(&Ain[buf][r0r + q*16][cg8]) = o;
    }
    if (t < TK) ngS[buf][t] = ngv;

    // 2. issue prefetch for tile+2 into the just-consumed registers
    if (tile + 2 < tile1) issueT(tile + 2, xv, xf, ngv);

    ldsbar();   // B2: Ain[buf]+ngS[buf] visible; prev pooling complete

    // 3. sliding-window flush (block-uniform; zeroing ordered by B3)
    int gfirst = ngS[buf][0];
    int glast;
    if (tile*TK + TK <= nNodes) glast = ngS[buf][TK-1];
    else {
      glast = gfirst;
      for (int i = TK-1; i > 0; --i){ int g = ngS[buf][i]; if (g >= 0){ glast = g; break; } }
    }
    if (gfirst >= 0 && glast >= gw0 + 16){
      for (int u = t; u < 16*H; u += 512){
        float vv = ((float*)Pacc)[u];
        if (vv != 0.f){
          int r = u >> 8, c = u & 255;
          atomicAdd(&pool[(size_t)(gw0 + r)*H + c], vv);
          ((float*)Pacc)[u] = 0.f;
        }
      }
      gw0 = gfirst;
    }

    // 4. MFMA: rows 0..31, cols wid*32..+32
    f32x4 acc0[2], acc1[2];
    #pragma unroll
    for (int r = 0; r < 2; ++r){ acc0[r] = (f32x4){0.f,0.f,0.f,0.f}; acc1[r] = (f32x4){0.f,0.f,0.f,0.f}; }
    #pragma unroll
    for (int kc = 0; kc < 8; ++kc){
      #pragma unroll
      for (int r = 0; r < 2; ++r){
        bf16x8 a = *(bf16x8*)(&Ain[buf][r*16 + l15][kc*32 + l4*8]);
        acc0[r] = __builtin_amdgcn_mfma_f32_16x16x32_bf16(a, Bf0[kc], acc0[r], 0, 0, 0);
        acc1[r] = __builtin_amdgcn_mfma_f32_16x16x32_bf16(a, Bf1[kc], acc1[r], 0, 0, 0);
      }
    }

    // 5. epilogue: hg gather (independent loads), dot, shuffle reduce
    float hv0[2][4], hv1[2][4];
    #pragma unroll
    for (int r = 0; r < 2; ++r)
      #pragma unroll
      for (int j = 0; j < 4; ++j){
        int g = ngS[buf][r*16 + l4*4 + j];
        if (g >= 0){
          const float* hgr = hg + (size_t)g*H + wid*32;
          hv0[r][j] = hgr[l15]; hv1[r][j] = hgr[16 + l15];
        } else { hv0[r][j] = 0.f; hv1[r][j] = 0.f; }
      }
    float p[2][4];
    #pragma unroll
    for (int r = 0; r < 2; ++r)
      #pragma unroll
      for (int j = 0; j < 4; ++j){
        int g = ngS[buf][r*16 + l4*4 + j];
        if (g >= 0){
          float h0 = fmaxf(acc0[r][j] + hv0[r][j], 0.f);
          float h1 = fmaxf(acc1[r][j] + hv1[r][j], 0.f);
          p[r][j] = w2v0*h0 + w2v1*h1;
        } else p[r][j] = 0.f;
      }
    #pragma unroll
    for (int off = 1; off < 16; off <<= 1){
      #pragma unroll
      for (int r = 0; r < 2; ++r)
        #pragma unroll
        for (int j = 0; j < 4; ++j) p[r][j] += __shfl_xor(p[r][j], off);
    }
    if (l15 == 0){
      #pragma unroll
      for (int r = 0; r < 2; ++r)
        #pragma unroll
        for (int j = 0; j < 4; ++j) partials[wid][r*16 + l4*4 + j] = p[r][j];
    }
    ldsbar();   // B3: partials visible (also orders Pacc zeroing before pooling)

    if (t < TK){
      float s = b2v;
      #pragma unroll
      for (int w = 0; w < 8; ++w) s += partials[w][t];
      gates[t] = sigmoidf_(s);
    }
    ldsbar();   // B4: gates visible

    // 6. weighted pooling into sliding-window Pacc
    {
      const int c2 = (t & 127) * 2;
      const int rr0 = (t >> 7) * 8;   // 4 row-groups of 8 rows

      float ax = 0.f, ay = 0.f;
      int cur = ngS[buf][rr0];
      if (cur >= 0){
        #pragma unroll
        for (int i = 0; i < 8; ++i){
          int g = ngS[buf][rr0 + i];
          if (g < 0) break;
          if (g != cur){
            int idx = cur - gw0;
            if (idx >= 0 && idx < 16){ atomicAdd(&Pacc[idx][c2], ax); atomicAdd(&Pacc[idx][c2+1], ay); }
            else { atomicAdd(&pool[(size_t)cur*H + c2], ax); atomicAdd(&pool[(size_t)cur*H + c2+1], ay); }
            ax = ay = 0.f; cur = g;
          }
          uint32_t av = *(const uint32_t*)(&Ain[buf][rr0 + i][c2]);
          float gv = gates[rr0 + i];
          ax += gv * bf2f((short)(uint16_t)(av & 0xFFFFu));
          ay += gv * bf2f((short)(uint16_t)(av >> 16));
        }
        int idx = cur - gw0;
        if (idx >= 0 && idx < 16){ atomicAdd(&Pacc[idx][c2], ax); atomicAdd(&Pacc[idx][c2+1], ay); }
        else { atomicAdd(&pool[(size_t)cur*H + c2], ax); atomicAdd(&pool[(size_t)cur*H + c2+1], ay); }
      }
    }
  };

  // prologue: fill both prefetch slots
  issueT(tile0, xvA, xfA, ngvA);
  if (tile0 + 1 < tile1) issueT(tile0 + 1, xvB, xfB, ngvB);

  int tile = tile0;
  while (true){
    body(tile, xvA, xfA, ngvA, 0);
    if (++tile >= tile1) break;
    body(tile, xvB, xfB, ngvB, 1);
    if (++tile >= tile1) break;
  }

  // final window flush
  ldsbar();
  for (int u = t; u < 16*H; u += 512){
    float vv = ((float*)Pacc)[u];
    if (vv != 0.f){
      int r = u >> 8, c = u & 255;
      atomicAdd(&pool[(size_t)(gw0 + r)*H + c], vv);
    }
  }
}

// ---------------- K2: fused GRU over 16 graphs/block ----------------
__global__ __launch_bounds__(256) void k2_gru(const float* __restrict__ pool,
    const float* __restrict__ counts, const float* __restrict__ repr_in,
    const short* __restrict__ wihbf, const short* __restrict__ whhbf,
    const float* __restrict__ bih, const float* __restrict__ bhh,
    float* __restrict__ repr_out){

  __shared__ short Anew[16][H + 8];
  __shared__ short Aold[16][H + 8];
  __shared__ float hold[16][H];
  __shared__ float srz[16][2*H];
  __shared__ float sni[16][H];
  __shared__ float snh[16][H];

  const int t    = threadIdx.x;
  const int wid  = t >> 6;
  const int lane = t & 63;
  const int l15  = lane & 15;
  const int l4   = lane >> 4;
  const int g0   = blockIdx.x * 16;

  for (int u = t; u < 16*H; u += 256){
    int row = u >> 8, c = u & 255;
    int g = g0 + row;
    float cnt = fmaxf(counts[g], 1.f);
    float rin = repr_in[(size_t)g*H + c];
    float nr  = pool[(size_t)g*H + c] / cnt;
    Anew[row][c] = f2bf(nr);
    Aold[row][c] = f2bf(rin);
    hold[row][c] = rin;
  }
  __syncthreads();

  f32x4 ai[12], ah[12];
  #pragma unroll
  for (int i = 0; i < 12; ++i){ ai[i] = (f32x4){0.f,0.f,0.f,0.f}; ah[i] = (f32x4){0.f,0.f,0.f,0.f}; }

  for (int kc = 0; kc < 8; ++kc){
    bf16x8 an = *(bf16x8*)(&Anew[l15][kc*32 + l4*8]);
    bf16x8 ao = *(bf16x8*)(&Aold[l15][kc*32 + l4*8]);
    #pragma unroll
    for (int nt = 0; nt < 12; ++nt){
      int n = wid*192 + nt*16 + l15;
      bf16x8 bi = *(const bf16x8*)(wihbf + (size_t)n*H + kc*32 + l4*8);
      bf16x8 bh = *(const bf16x8*)(whhbf + (size_t)n*H + kc*32 + l4*8);
      ai[nt] = __builtin_amdgcn_mfma_f32_16x16x32_bf16(an, bi, ai[nt], 0, 0, 0);
      ah[nt] = __builtin_amdgcn_mfma_f32_16x16x32_bf16(ao, bh, ah[nt], 0, 0, 0);
    }
  }

  #pragma unroll
  for (int nt = 0; nt < 12; ++nt){
    int n = wid*192 + nt*16 + l15;
    float bi = bih[n], bh = bhh[n];
    #pragma unroll
    for (int r = 0; r < 4; ++r){
      int row = l4*4 + r;
      float si = ai[nt][r] + bi;
      float sh = ah[nt][r] + bh;
      if (n < 2*H) srz[row][n] = si + sh;
      else { sni[row][n - 2*H] = si; snh[row][n - 2*H] = sh; }
    }
  }
  __syncthreads();

  for (int u = t; u < 16*H; u += 256){
    int row = u >> 8, c = u & 255;
    float rr = sigmoidf_(srz[row][c]);
    float zz = sigmoidf_(srz[row][H + c]);
    float nn = tanhf(sni[row][c] + rr * snh[row][c]);
    float hv = (1.f - zz) * nn + zz * hold[row][c];
    repr_out[(size_t)(g0 + row)*H + c] = fmaxf(hv, 0.f);
  }
}

extern "C" void kernel_launch(void* const* d_in, const int* in_sizes, int n_in,
                              void* d_out, int out_size, void* d_ws, size_t ws_size,
                              hipStream_t stream){
  const float* x    = (const float*)d_in[0];
  const float* w1   = (const float*)d_in[1];
  const float* b1   = (const float*)d_in[2];
  const float* w2   = (const float*)d_in[3];
  const float* b2   = (const float*)d_in[4];
  const float* wih  = (const float*)d_in[5];
  const float* whh  = (const float*)d_in[6];
  const float* bih  = (const float*)d_in[7];
  const float* bhh  = (const float*)d_in[8];
  const int*   batch= (const int*)d_in[9];
  const int N = in_sizes[9];

  char* ws = (char*)d_ws;
  short* w1bf   = (short*)(ws + 0);            // 128 KB
  short* wihbf  = (short*)(ws + (1u<<17));     // 384 KB @128K
  short* whhbf  = (short*)(ws + (1u<<19));     // 384 KB @512K
  float* counts = (float*)(ws + 917504);       // 16 KB @896K
  float* pool   = (float*)(ws + (1u<<20));     // 4 MB @1M
  float* repr   = (float*)(ws + (1u<<20) + (1u<<22)); // 4 MB @5M
  float* hg     = (float*)d_out;               // 4 MB, dead before final k2 writes output
  float* outp   = (float*)d_out;

  const size_t XBF_OFF = (size_t)16u << 20;    // 16 MB
  const bool useXbf = ws_size >= XBF_OFF + (size_t)N * H * sizeof(short);
  short* xbf = useXbf ? (short*)(ws + XBF_OFF) : nullptr;

  const int nTiles  = (N + TK - 1) / TK;       // 15625
  const int nBlkK1  = 512;                     // 2 persistent blocks / CU
  const int nBlk0   = (N + T0 - 1) / T0;

  conv_w<<<768, 256, 0, stream>>>(w1, wih, whh, w1bf, wihbf, whhbf);

  hipMemsetAsync(counts, 0, G*sizeof(float), stream);
  hipMemsetAsync(pool, 0, (size_t)G*H*sizeof(float), stream);
  k0_pool<<<nBlk0, 512, 0, stream>>>(x, batch, pool, counts, xbf, N);
  k0b_div<<<G*H/256, 256, 0, stream>>>(pool, counts, repr);

  for (int ts = 0; ts < 2; ++ts){
    kT_hg<<<G/16, 256, 0, stream>>>(repr, w1bf, b1, hg);
    hipMemsetAsync(pool, 0, (size_t)G*H*sizeof(float), stream);
    if (useXbf)
      k1_gate<true><<<nBlkK1, 512, 0, stream>>>(x, xbf, batch, hg, w1bf, w2, b2, pool, N, nTiles, nBlkK1);
    else
      k1_gate<false><<<nBlkK1, 512, 0, stream>>>(x, xbf, batch, hg, w1bf, w2, b2, pool, N, nTiles, nBlkK1);
    k2_gru<<<G/16, 256, 0, stream>>>(pool, counts, repr, wihbf, whhbf, bih, bhh,
                                     (ts == 0) ? repr : outp);
  }
}